// Round 4
// baseline (332.474 us; speedup 1.0000x reference)
//
#include <hip/hip_runtime.h>
#include <hip/hip_cooperative_groups.h>

namespace cg = cooperative_groups;

#define BB 8
#define NN 32
#define SS 8
#define HH 512
#define WW 512
#define KK 9
#define RR 4
#define NKP (BB * NN * SS)          // 2048 keypoints
#define NTAP (KK * KK)              // 81 taps per stamp
#define GRID 1024                   // 4 blocks/CU * 256 CUs
#define TPB 256
#define NTHR (GRID * TPB)           // 262144
#define TOTAL4 (BB * HH * WW / 4)   // 524288 float4 pixels of bm

// Single cooperative kernel: zero -> scatter -> MSE partials -> final.
// NOTE: no thread may return before the grid.sync()s (deadlock), so all
// phase work is guarded by ifs, not early exits.
__global__ __launch_bounds__(TPB, 4) void fused_all(
    const float* __restrict__ pred, const int* __restrict__ target,
    const float* __restrict__ gk, float* __restrict__ bm,
    double* __restrict__ partial, float* __restrict__ out) {
    cg::grid_group grid = cg::this_grid();
    const int tid = blockIdx.x * TPB + threadIdx.x;

    // ---- phase 0: zero the 8 MB belive map (2 float4 per thread) ----
    float4* bm4 = (float4*)bm;
    bm4[tid] = make_float4(0.f, 0.f, 0.f, 0.f);
    bm4[tid + NTHR] = make_float4(0.f, 0.f, 0.f, 0.f);

    grid.sync();

    // ---- phase 1: scatter gaussian taps (one thread per keypoint-tap) ----
    if (tid < NKP * NTAP) {
        int tap = tid % NTAP;
        int kp = tid / NTAP;
        int s = kp % SS;
        int n = (kp / SS) % NN;
        int b = kp / (NN * SS);
        int x = target[kp * 2], y = target[kp * 2 + 1];
        // jax .set(1.0) semantics: duplicate (b,s,y,x) counts once
        bool dup = false;
        for (int np = 0; np < n; ++np) {
            const int* tp = target + (((size_t)b * NN + np) * SS + s) * 2;
            if (tp[0] == x && tp[1] == y) { dup = true; break; }
        }
        if (!dup) {
            int yy = y + tap / KK - RR;
            int xx = x + tap % KK - RR;
            if (yy >= 0 && yy < HH && xx >= 0 && xx < WW)
                atomicAdd(&bm[(size_t)b * HH * WW + yy * WW + xx], gk[tap]);
        }
    }

    grid.sync();

    // ---- phase 2: fused MSE partial sums ----
    float local = 0.f;
    for (int i = tid; i < TOTAL4; i += NTHR) {
        int b = i / (HH * WW / 4);
        int hw4 = i % (HH * WW / 4);
        float4 bmv = ((const float4*)bm)[i];
        const float* pb = pred + (size_t)b * SS * HH * WW;
#pragma unroll
        for (int s = 0; s < SS; ++s) {
            float4 p = ((const float4*)(pb + (size_t)s * HH * WW))[hw4];
            float d0 = p.x - bmv.x;
            float d1 = p.y - bmv.y;
            float d2 = p.z - bmv.z;
            float d3 = p.w - bmv.w;
            local += d0 * d0 + d1 * d1 + d2 * d2 + d3 * d3;
        }
    }
    for (int off = 32; off; off >>= 1) local += __shfl_down(local, off);
    __shared__ float ws_f[4];
    int lane = threadIdx.x & 63, wid = threadIdx.x >> 6;
    if (lane == 0) ws_f[wid] = local;
    __syncthreads();
    if (threadIdx.x == 0)
        partial[blockIdx.x] = (double)(ws_f[0] + ws_f[1] + ws_f[2] + ws_f[3]);

    grid.sync();

    // ---- phase 3: block 0 sums the 1024 partials ----
    if (blockIdx.x == 0) {
        double l2 = 0.0;
        for (int i = threadIdx.x; i < GRID; i += TPB) l2 += partial[i];
        for (int off = 32; off; off >>= 1) l2 += __shfl_down(l2, off);
        __shared__ double ws_d[4];
        if (lane == 0) ws_d[wid] = l2;
        __syncthreads();
        if (threadIdx.x == 0)
            out[0] = (float)((ws_d[0] + ws_d[1] + ws_d[2] + ws_d[3]) /
                             (double)((size_t)BB * SS * HH * WW));
    }
}

// ---------------- fallback path (proven round-3 pipeline) ----------------
__global__ void zero_bm(float4* __restrict__ bm4) {
    int i = blockIdx.x * blockDim.x + threadIdx.x;
    bm4[i] = make_float4(0.f, 0.f, 0.f, 0.f);
}

__global__ void scatter_gauss(const int* __restrict__ target,
                              const float* __restrict__ gk,
                              float* __restrict__ bm) {
    int idx = blockIdx.x * blockDim.x + threadIdx.x;
    if (idx >= NKP * NTAP) return;
    int tap = idx % NTAP;
    int kp = idx / NTAP;
    int s = kp % SS;
    int n = (kp / SS) % NN;
    int b = kp / (NN * SS);
    int x = target[kp * 2], y = target[kp * 2 + 1];
    for (int np = 0; np < n; ++np) {
        const int* tp = target + (((size_t)b * NN + np) * SS + s) * 2;
        if (tp[0] == x && tp[1] == y) return;
    }
    int yy = y + tap / KK - RR;
    int xx = x + tap % KK - RR;
    if (yy < 0 || yy >= HH || xx < 0 || xx >= WW) return;
    atomicAdd(&bm[(size_t)b * HH * WW + yy * WW + xx], gk[tap]);
}

__global__ void reduce_loss(const float* __restrict__ pred,
                            const float* __restrict__ bm,
                            double* __restrict__ partial) {
    float local = 0.f;
    for (int i = blockIdx.x * blockDim.x + threadIdx.x; i < TOTAL4;
         i += gridDim.x * blockDim.x) {
        int b = i / (HH * WW / 4);
        int hw4 = i % (HH * WW / 4);
        float4 bmv = ((const float4*)bm)[i];
        const float* pb = pred + (size_t)b * SS * HH * WW;
#pragma unroll
        for (int s = 0; s < SS; ++s) {
            float4 p = ((const float4*)(pb + (size_t)s * HH * WW))[hw4];
            float d0 = p.x - bmv.x;
            float d1 = p.y - bmv.y;
            float d2 = p.z - bmv.z;
            float d3 = p.w - bmv.w;
            local += d0 * d0 + d1 * d1 + d2 * d2 + d3 * d3;
        }
    }
    for (int off = 32; off; off >>= 1) local += __shfl_down(local, off);
    __shared__ float warp_s[4];
    int lane = threadIdx.x & 63, wid = threadIdx.x >> 6;
    if (lane == 0) warp_s[wid] = local;
    __syncthreads();
    if (threadIdx.x == 0)
        partial[blockIdx.x] = (double)(warp_s[0] + warp_s[1] + warp_s[2] + warp_s[3]);
}

__global__ void final_reduce(const double* __restrict__ partial,
                             float* __restrict__ out) {
    double local = 0.0;
    for (int i = threadIdx.x; i < GRID; i += 256) local += partial[i];
    for (int off = 32; off; off >>= 1) local += __shfl_down(local, off);
    __shared__ double warp_s[4];
    int lane = threadIdx.x & 63, wid = threadIdx.x >> 6;
    if (lane == 0) warp_s[wid] = local;
    __syncthreads();
    if (threadIdx.x == 0)
        out[0] = (float)((warp_s[0] + warp_s[1] + warp_s[2] + warp_s[3]) /
                         (double)((size_t)BB * SS * HH * WW));
}

extern "C" void kernel_launch(void* const* d_in, const int* in_sizes, int n_in,
                              void* d_out, int out_size, void* d_ws, size_t ws_size,
                              hipStream_t stream) {
    const float* pred = (const float*)d_in[0];     // (B,S,H,W) f32
    const int* target = (const int*)d_in[1];       // (B,N,S,2) i32
    const float* gk   = (const float*)d_in[2];     // (9,9) f32

    float* bm       = (float*)d_ws;                                   // 8 MB
    double* partial = (double*)((char*)d_ws + (size_t)BB * HH * WW * 4);
    float* outp     = (float*)d_out;

    // Host-side occupancy check (no stream ops): coop needs all 1024 blocks
    // co-resident (4 blocks/CU on 256 CUs).
    int maxb = 0;
    hipError_t oe = hipOccupancyMaxActiveBlocksPerMultiprocessor(
        &maxb, (const void*)fused_all, TPB, 0);
    bool coop_ok = (oe == hipSuccess && maxb >= 4);

    if (coop_ok) {
        void* args[] = {(void*)&pred, (void*)&target, (void*)&gk,
                        (void*)&bm, (void*)&partial, (void*)&outp};
        hipError_t e = hipLaunchCooperativeKernel(
            (void*)fused_all, dim3(GRID), dim3(TPB), args, 0, stream);
        if (e == hipSuccess) return;
    }

    // fallback: round-3 four-kernel pipeline
    zero_bm<<<TOTAL4 / 256, 256, 0, stream>>>((float4*)bm);
    scatter_gauss<<<(NKP * NTAP + 255) / 256, 256, 0, stream>>>(target, gk, bm);
    reduce_loss<<<GRID, 256, 0, stream>>>(pred, bm, partial);
    final_reduce<<<1, 256, 0, stream>>>(partial, outp);
}

// Round 5
// 22.328 us; speedup vs baseline: 14.8907x; 14.8907x over previous
//
#include <hip/hip_runtime.h>

#define BB 8
#define NN 32
#define SS 8
#define HH 512
#define WW 512
#define KK 9
#define RR 4
#define TPB 256
#define ROWS_PER_BLK 2
#define BLKS_PER_IMG (HH / ROWS_PER_BLK)   // 256
#define GRID (BB * BLKS_PER_IMG)           // 2048
#define KPB (NN * SS)                      // 256 keypoints per batch image

// One block = one 2-row strip of one batch image. Stage the batch's 256
// keypoints in LDS, dedup (jax .set semantics), filter to the strip, then
// compute the belive map per-pixel in registers and fuse the MSE. No dense
// bm buffer, no zero pass, no scatter pass, no global atomics.
__global__ __launch_bounds__(TPB) void fused_loss(
    const float* __restrict__ pred, const int* __restrict__ target,
    const float* __restrict__ gk, double* __restrict__ partial) {
    __shared__ float g[KK * KK];
    __shared__ int kx[KPB], ky[KPB];
    __shared__ int lx[KPB], ly[KPB];
    __shared__ int lcount;

    const int b = blockIdx.x / BLKS_PER_IMG;
    const int strip = blockIdx.x % BLKS_PER_IMG;
    const int y0 = strip * ROWS_PER_BLK;
    const int t = threadIdx.x;

    if (t < KK * KK) g[t] = gk[t];
    if (t == 0) lcount = 0;

    // stage all keypoints of batch b (one per thread; KPB == TPB)
    const int* tg = target + (size_t)b * KPB * 2;
    kx[t] = tg[t * 2];
    ky[t] = tg[t * 2 + 1];
    __syncthreads();

    // dedup (duplicate (b,s,y,x) counts once -> keep only first n) + strip bbox
    {
        int n = t >> 3, s = t & 7;   // kp index = n*SS + s
        int x = kx[t], y = ky[t];
        bool keep = (y >= y0 - RR) && (y <= y0 + ROWS_PER_BLK - 1 + RR);
        if (keep) {
            for (int np = 0; np < n; ++np) {
                int j = np * SS + s;
                if (kx[j] == x && ky[j] == y) { keep = false; break; }
            }
        }
        if (keep) {
            int slot = atomicAdd(&lcount, 1);
            lx[slot] = x;
            ly[slot] = y;
        }
    }
    __syncthreads();
    const int cnt = lcount;  // expected ~5

    // each thread: 4 consecutive pixels of one row (128 threads/row)
    const int row = y0 + (t >> 7);
    const int x4 = (t & 127) * 4;

    float bmv[4] = {0.f, 0.f, 0.f, 0.f};
    for (int i = 0; i < cnt; ++i) {
        int dy = row - ly[i];
        if (dy < -RR || dy > RR) continue;
        const float* grow = &g[(dy + RR) * KK];
        int dx0 = x4 - lx[i];
#pragma unroll
        for (int j = 0; j < 4; ++j) {
            int dx = dx0 + j;
            if (dx >= -RR && dx <= RR) bmv[j] += grow[dx + RR];
        }
    }

    // fused MSE over the 8 channels
    const float* pb = pred + ((size_t)b * SS) * HH * WW + (size_t)row * WW + x4;
    float local = 0.f;
#pragma unroll
    for (int s = 0; s < SS; ++s) {
        float4 p = *(const float4*)(pb + (size_t)s * HH * WW);
        float d0 = p.x - bmv[0];
        float d1 = p.y - bmv[1];
        float d2 = p.z - bmv[2];
        float d3 = p.w - bmv[3];
        local += d0 * d0 + d1 * d1 + d2 * d2 + d3 * d3;
    }

    // wave(64) shuffle reduce -> block partial (no global atomics)
    for (int off = 32; off; off >>= 1) local += __shfl_down(local, off);
    __shared__ float ws_f[4];
    int lane = t & 63, wid = t >> 6;
    if (lane == 0) ws_f[wid] = local;
    __syncthreads();
    if (t == 0)
        partial[blockIdx.x] = (double)(ws_f[0] + ws_f[1] + ws_f[2] + ws_f[3]);
}

// Single block: sum GRID doubles, write the mean.
__global__ void final_reduce(const double* __restrict__ partial,
                             float* __restrict__ out) {
    double local = 0.0;
    for (int i = threadIdx.x; i < GRID; i += 256) local += partial[i];
    for (int off = 32; off; off >>= 1) local += __shfl_down(local, off);
    __shared__ double warp_s[4];
    int lane = threadIdx.x & 63, wid = threadIdx.x >> 6;
    if (lane == 0) warp_s[wid] = local;
    __syncthreads();
    if (threadIdx.x == 0)
        out[0] = (float)((warp_s[0] + warp_s[1] + warp_s[2] + warp_s[3]) /
                         (double)((size_t)BB * SS * HH * WW));
}

extern "C" void kernel_launch(void* const* d_in, const int* in_sizes, int n_in,
                              void* d_out, int out_size, void* d_ws, size_t ws_size,
                              hipStream_t stream) {
    const float* pred = (const float*)d_in[0];     // (B,S,H,W) f32
    const int* target = (const int*)d_in[1];       // (B,N,S,2) i32
    const float* gk   = (const float*)d_in[2];     // (9,9) f32

    double* partial = (double*)d_ws;               // GRID doubles = 16 KB

    fused_loss<<<GRID, TPB, 0, stream>>>(pred, target, gk, partial);
    final_reduce<<<1, 256, 0, stream>>>(partial, (float*)d_out);
}

// Round 6
// 21.575 us; speedup vs baseline: 15.4102x; 1.0349x over previous
//
#include <hip/hip_runtime.h>

#define BB 8
#define NN 32
#define SS 8
#define HH 512
#define WW 512
#define KK 9
#define RR 4
#define TPB 256
#define ROWS_PER_BLK 4
#define BLKS_PER_IMG (HH / ROWS_PER_BLK)   // 128
#define GRID (BB * BLKS_PER_IMG)           // 1024
#define KPB (NN * SS)                      // 256 keypoints per batch image

// One block = one 4-row strip of one batch image. Stage the batch's 256
// keypoints in LDS, dedup (jax .set semantics), filter to the strip, then
// compute the belive map per-pixel in registers and fuse the MSE. Each wave
// owns one row: load A = px [lane*4, ...), load B = px [256+lane*4, ...) --
// two fully contiguous 1 KB wave segments per channel.
__global__ __launch_bounds__(TPB) void fused_loss(
    const float* __restrict__ pred, const int* __restrict__ target,
    const float* __restrict__ gk, double* __restrict__ partial) {
    __shared__ float g[KK * KK];
    __shared__ int kx[KPB], ky[KPB];
    __shared__ int lx[KPB], ly[KPB];
    __shared__ int lcount;

    const int b = blockIdx.x / BLKS_PER_IMG;
    const int strip = blockIdx.x % BLKS_PER_IMG;
    const int y0 = strip * ROWS_PER_BLK;
    const int t = threadIdx.x;

    if (t < KK * KK) g[t] = gk[t];
    if (t == 0) lcount = 0;

    // stage all keypoints of batch b (one per thread; KPB == TPB)
    const int* tg = target + (size_t)b * KPB * 2;
    kx[t] = tg[t * 2];
    ky[t] = tg[t * 2 + 1];
    __syncthreads();

    // dedup (duplicate (b,s,y,x) counts once -> keep only first n) + strip bbox
    {
        int n = t >> 3, s = t & 7;   // kp index = n*SS + s
        int x = kx[t], y = ky[t];
        bool keep = (y >= y0 - RR) && (y <= y0 + ROWS_PER_BLK - 1 + RR);
        if (keep) {
            for (int np = 0; np < n; ++np) {
                int j = np * SS + s;
                if (kx[j] == x && ky[j] == y) { keep = false; break; }
            }
        }
        if (keep) {
            int slot = atomicAdd(&lcount, 1);
            lx[slot] = x;
            ly[slot] = y;
        }
    }
    __syncthreads();
    const int cnt = lcount;  // expected ~6

    // wave = row; two contiguous quads per thread
    const int lane = t & 63;
    const int row = y0 + (t >> 6);
    const int xA = lane * 4;
    const int xB = 256 + lane * 4;

    float bmA[4] = {0.f, 0.f, 0.f, 0.f};
    float bmB[4] = {0.f, 0.f, 0.f, 0.f};
    for (int i = 0; i < cnt; ++i) {
        int dy = row - ly[i];
        if (dy < -RR || dy > RR) continue;   // wave-uniform branch
        const float* grow = &g[(dy + RR) * KK];
        int dA = xA - lx[i];
        int dB = xB - lx[i];
#pragma unroll
        for (int j = 0; j < 4; ++j) {
            int da = dA + j;
            if (da >= -RR && da <= RR) bmA[j] += grow[da + RR];
            int db = dB + j;
            if (db >= -RR && db <= RR) bmB[j] += grow[db + RR];
        }
    }

    // fused MSE over the 8 channels, 2 float4 per channel
    const float* pb = pred + ((size_t)b * SS) * HH * WW + (size_t)row * WW;
    float local = 0.f;
#pragma unroll
    for (int s = 0; s < SS; ++s) {
        const float* prow = pb + (size_t)s * HH * WW;
        float4 pA = *(const float4*)(prow + xA);
        float4 pB = *(const float4*)(prow + xB);
        float a0 = pA.x - bmA[0], a1 = pA.y - bmA[1];
        float a2 = pA.z - bmA[2], a3 = pA.w - bmA[3];
        float b0 = pB.x - bmB[0], b1 = pB.y - bmB[1];
        float b2 = pB.z - bmB[2], b3 = pB.w - bmB[3];
        local += a0 * a0 + a1 * a1 + a2 * a2 + a3 * a3;
        local += b0 * b0 + b1 * b1 + b2 * b2 + b3 * b3;
    }

    // wave(64) shuffle reduce -> block partial (no global atomics)
    for (int off = 32; off; off >>= 1) local += __shfl_down(local, off);
    __shared__ float ws_f[4];
    int wid = t >> 6;
    if (lane == 0) ws_f[wid] = local;
    __syncthreads();
    if (t == 0)
        partial[blockIdx.x] = (double)(ws_f[0] + ws_f[1] + ws_f[2] + ws_f[3]);
}

// Single block: sum GRID doubles, write the mean.
__global__ void final_reduce(const double* __restrict__ partial,
                             float* __restrict__ out) {
    double local = 0.0;
    for (int i = threadIdx.x; i < GRID; i += 256) local += partial[i];
    for (int off = 32; off; off >>= 1) local += __shfl_down(local, off);
    __shared__ double warp_s[4];
    int lane = threadIdx.x & 63, wid = threadIdx.x >> 6;
    if (lane == 0) warp_s[wid] = local;
    __syncthreads();
    if (threadIdx.x == 0)
        out[0] = (float)((warp_s[0] + warp_s[1] + warp_s[2] + warp_s[3]) /
                         (double)((size_t)BB * SS * HH * WW));
}

extern "C" void kernel_launch(void* const* d_in, const int* in_sizes, int n_in,
                              void* d_out, int out_size, void* d_ws, size_t ws_size,
                              hipStream_t stream) {
    const float* pred = (const float*)d_in[0];     // (B,S,H,W) f32
    const int* target = (const int*)d_in[1];       // (B,N,S,2) i32
    const float* gk   = (const float*)d_in[2];     // (9,9) f32

    double* partial = (double*)d_ws;               // GRID doubles = 8 KB

    fused_loss<<<GRID, TPB, 0, stream>>>(pred, target, gk, partial);
    final_reduce<<<1, 256, 0, stream>>>(partial, (float*)d_out);
}